// Round 9
// baseline (597.917 us; speedup 1.0000x reference)
//
#include <hip/hip_runtime.h>

#define UCNT 100000
#define NN   150000
#define DD   64
#define EE   2000000
#define EPSV 0.2f

#define SCAN_BLK   256
#define SCAN_ELEMS 1024
#define NBLK       ((NN + SCAN_ELEMS - 1) / SCAN_ELEMS)   // 147

#define TEAMS     8
#define TEAMROWS  (NN / TEAMS)                            // 18750
#define CHUNKS    256
#define CE        ((EE + CHUNKS - 1) / CHUNKS)            // 7813

// ---- CSR build ----------------------------------------------------------

__global__ void hist_kernel(const int* __restrict__ rows, int* __restrict__ counts) {
    int e = blockIdx.x * blockDim.x + threadIdx.x;
    if (e < EE) atomicAdd(&counts[rows[e]], 1);
}

// per-block exclusive scan (4 elems/thread), emits block sums
__global__ void scanA(const int* __restrict__ counts, int* __restrict__ base,
                      int* __restrict__ bsum) {
    int b = blockIdx.x, t = threadIdx.x;
    int i0 = b * SCAN_ELEMS + t * 4;
    int c0 = (i0 + 0 < NN) ? counts[i0 + 0] : 0;
    int c1 = (i0 + 1 < NN) ? counts[i0 + 1] : 0;
    int c2 = (i0 + 2 < NN) ? counts[i0 + 2] : 0;
    int c3 = (i0 + 3 < NN) ? counts[i0 + 3] : 0;
    int s = c0 + c1 + c2 + c3;
    __shared__ int lds[SCAN_BLK];
    lds[t] = s;
    __syncthreads();
    for (int off = 1; off < SCAN_BLK; off <<= 1) {
        int add = (t >= off) ? lds[t - off] : 0;
        __syncthreads();
        lds[t] += add;
        __syncthreads();
    }
    int excl = lds[t] - s;
    if (i0 + 0 < NN) base[i0 + 0] = excl;
    if (i0 + 1 < NN) base[i0 + 1] = excl + c0;
    if (i0 + 2 < NN) base[i0 + 2] = excl + c0 + c1;
    if (i0 + 3 < NN) base[i0 + 3] = excl + c0 + c1 + c2;
    if (t == SCAN_BLK - 1) bsum[b] = lds[t];
}

// exclusive scan of the (<=256) block sums, single block
__global__ void scanB(int* __restrict__ bsum) {
    int t = threadIdx.x;
    int v = (t < NBLK) ? bsum[t] : 0;
    __shared__ int lds[SCAN_BLK];
    lds[t] = v;
    __syncthreads();
    for (int off = 1; off < SCAN_BLK; off <<= 1) {
        int add = (t >= off) ? lds[t - off] : 0;
        __syncthreads();
        lds[t] += add;
        __syncthreads();
    }
    if (t < NBLK) bsum[t] = lds[t] - v;
}

// add block offsets; also zero the scatter cursor (saves a memset dispatch)
__global__ void scanC(int* __restrict__ base, const int* __restrict__ bsum,
                      int* __restrict__ cursor) {
    int b = blockIdx.x, t = threadIdx.x;
    int add = bsum[b];
    int i0 = b * SCAN_ELEMS + t * 4;
    if (i0 + 0 < NN) { base[i0 + 0] += add; cursor[i0 + 0] = 0; }
    if (i0 + 1 < NN) { base[i0 + 1] += add; cursor[i0 + 1] = 0; }
    if (i0 + 2 < NN) { base[i0 + 2] += add; cursor[i0 + 2] = 0; }
    if (i0 + 3 < NN) { base[i0 + 3] += add; cursor[i0 + 3] = 0; }
}

// team-sliced scatter: team = blockIdx & 7 round-robins onto the 8 XCDs;
// team j only handles rows in its slice, so its cursor/ceid/cpair slices
// stay in one XCD's L2 and dirty lines fill before eviction. Each chunk of
// the edge list is scanned by 8 blocks (one per team). Writes the (col,val)
// pair at scatter time (coalesced source reads); order canonicalized later.
__global__ void scatter_team(const int* __restrict__ rows, const int* __restrict__ cols,
                             const float* __restrict__ vals,
                             const int* __restrict__ base, int* __restrict__ cursor,
                             unsigned* __restrict__ ceid, int2* __restrict__ cpair) {
    int team  = blockIdx.x & (TEAMS - 1);
    int chunk = blockIdx.x / TEAMS;
    int lo = team * TEAMROWS, hi = lo + TEAMROWS;
    int e0 = chunk * CE;
    int e1 = e0 + CE; if (e1 > EE) e1 = EE;
    for (int e = e0 + threadIdx.x; e < e1; e += 256) {
        int r = rows[e];
        if (r >= lo && r < hi) {
            int pos = base[r] + atomicAdd(&cursor[r], 1);
            ceid[pos]  = (unsigned)e;
            cpair[pos] = make_int2(cols[e], __float_as_int(vals[e]));
        }
    }
}

// canonicalize: one 64-lane wave per row; bitonic sort by edge id carrying
// the (col,val) payload through the network; write back sorted pairs
// coalesced. All loads/stores coalesced; no random gathers.
__global__ void rowsort_pair(const int* __restrict__ base, const int* __restrict__ counts,
                             unsigned* __restrict__ ceid, int2* __restrict__ cpair) {
    int row = blockIdx.x * 4 + (threadIdx.x >> 6);
    if (row >= NN) return;
    int lane = threadIdx.x & 63;
    int s = base[row], n = counts[row];
    if (n <= 1) return;
    if (n <= 64) {
        unsigned key = 0xFFFFFFFFu;                   // pad sorts to the end
        int pc = 0, pv = 0;
        if (lane < n) {
            key = ceid[s + lane];
            int2 p = cpair[s + lane];
            pc = p.x; pv = p.y;
        }
        #pragma unroll
        for (int k = 2; k <= 64; k <<= 1) {
            #pragma unroll
            for (int j = k >> 1; j > 0; j >>= 1) {
                unsigned okey = __shfl_xor(key, j, 64);
                int      oc   = __shfl_xor(pc,  j, 64);
                int      ov   = __shfl_xor(pv,  j, 64);
                bool up    = ((lane & k) == 0);
                bool lower = ((lane & j) == 0);
                bool takeOther = (lower == up) ? (okey < key) : (okey > key);
                if (takeOther) { key = okey; pc = oc; pv = ov; }
            }
        }
        if (lane < n) cpair[s + lane] = make_int2(pc, pv);
    } else if (lane == 0) {                           // ~never (Poisson mean 13)
        for (int i = 1; i < n; ++i) {
            unsigned kk = ceid[s + i];
            int2 pp = cpair[s + i];
            int j = i - 1;
            while (j >= 0 && ceid[s + j] > kk) {
                ceid[s + j + 1]  = ceid[s + j];
                cpair[s + j + 1] = cpair[s + j];
                --j;
            }
            ceid[s + j + 1]  = kk;
            cpair[s + j + 1] = pp;
        }
    }
}

// ---- fused gather-SPMM + noise perturbation + output accumulation -------
// 16 lanes per row, 4 rows per wave, 16 rows per block (round-8-proven).
// Per-dim summation order is exactly e0<e1<... (eid ascending).
__device__ __forceinline__ float sgnf(float v) {
    return (v > 0.0f) ? 1.0f : ((v < 0.0f) ? -1.0f : 0.0f);
}

__global__ __launch_bounds__(256) void
spmm_fused(const int* __restrict__ base, const int* __restrict__ counts,
           const int2* __restrict__ cpair,
           const float* __restrict__ xu, const float* __restrict__ xi,
           int usplit,
           const float* __restrict__ noise_k,
           float* __restrict__ xout,
           const float* __restrict__ cl_in,
           const float* __restrict__ xa_in,
           float* __restrict__ outp,
           int k) {
    int tid = blockIdx.x * 256 + threadIdx.x;
    int row = tid >> 4;                   // 16 lanes per row
    if (row >= NN) return;
    int lane = threadIdx.x & 63;
    int q  = lane & 15;                   // dim quad within row
    int gb = lane & 48;                   // group base lane within wave

    int s = base[row];
    int n = counts[row];

    // hoisted independent loads
    size_t ro = (size_t)row * DD + q * 4;
    float4 nv = *(const float4*)(noise_k + ro);
    float4 clv = make_float4(0.f, 0.f, 0.f, 0.f);
    float4 xav = make_float4(0.f, 0.f, 0.f, 0.f);
    if (k == 2) {
        clv = *(const float4*)(cl_in + ro);
        xav = *(const float4*)(xa_in + ro);
    }

    float4 acc = make_float4(0.f, 0.f, 0.f, 0.f);
    for (int chunk = 0; chunk < n; chunk += 16) {      // group-uniform bound
        int rem = n - chunk;
        int2 p = make_int2(0, 0);
        if (q < rem) p = cpair[s + chunk + q];         // coalesced 128B/row
        int m = (rem < 16) ? rem : 16;
        for (int i = 0; i < m; ++i) {                  // group-uniform bound
            int   c = __shfl(p.x, gb + i, 64);
            float v = __int_as_float(__shfl(p.y, gb + i, 64));
            const float* xr = (c < usplit) ? (xu + (size_t)c * DD)
                                           : (xi + (size_t)(c - usplit) * DD);
            float4 xv = ((const float4*)xr)[q];
            acc.x += v * xv.x;
            acc.y += v * xv.y;
            acc.z += v * xv.z;
            acc.w += v * xv.w;
        }
    }

    // noise L2 norm within the 16-lane group (xor 1,2,4,8 stays in-group)
    float ss = nv.x * nv.x + nv.y * nv.y + nv.z * nv.z + nv.w * nv.w;
    ss += __shfl_xor(ss, 1, 64);
    ss += __shfl_xor(ss, 2, 64);
    ss += __shfl_xor(ss, 4, 64);
    ss += __shfl_xor(ss, 8, 64);
    float scale = EPSV / fmaxf(sqrtf(ss), 1e-12f);

    float4 ego;
    ego.x = acc.x + sgnf(acc.x) * nv.x * scale;
    ego.y = acc.y + sgnf(acc.y) * nv.y * scale;
    ego.z = acc.z + sgnf(acc.z) * nv.z * scale;
    ego.w = acc.w + sgnf(acc.w) * nv.w * scale;

    if (k == 2) {
        const float inv3 = 1.0f / 3.0f;
        float4 o;
        o.x = (clv.x + xav.x + ego.x) * inv3;
        o.y = (clv.y + xav.y + ego.y) * inv3;
        o.z = (clv.z + xav.z + ego.z) * inv3;
        o.w = (clv.w + xav.w + ego.w) * inv3;
        *(float4*)(outp + ro) = o;
    } else {
        *(float4*)(xout + ro) = ego;
    }
}

extern "C" void kernel_launch(void* const* d_in, const int* in_sizes, int n_in,
                              void* d_out, int out_size, void* d_ws, size_t ws_size,
                              hipStream_t stream) {
    const float* ue    = (const float*)d_in[0];
    const float* ie    = (const float*)d_in[1];
    const int*   erow  = (const int*)  d_in[2];
    const int*   ecol  = (const int*)  d_in[3];
    const float* evals = (const float*)d_in[4];
    const float* noise = (const float*)d_in[5];
    float* out = (float*)d_out;

    // workspace layout
    char* w = (char*)d_ws;
    float* x_a   = (float*)w;                    w += (size_t)NN * DD * sizeof(float);
    int*   counts= (int*)w;                      w += (size_t)NN * sizeof(int);
    int*   basep = (int*)w;                      w += (size_t)NN * sizeof(int);
    int*   cursor= (int*)w;                      w += (size_t)NN * sizeof(int);
    int*   bsum  = (int*)w;                      w += 256 * sizeof(int);
    int2*  cpair = (int2*)w;                     w += (size_t)EE * sizeof(int2);
    unsigned* ceid = (unsigned*)w;               w += (size_t)EE * sizeof(unsigned);

    hipMemsetAsync(counts, 0, (size_t)NN * sizeof(int), stream);

    int blk = 256;
    hist_kernel<<<(EE + blk - 1) / blk, blk, 0, stream>>>(erow, counts);
    scanA<<<NBLK, SCAN_BLK, 0, stream>>>(counts, basep, bsum);
    scanB<<<1, SCAN_BLK, 0, stream>>>(bsum);
    scanC<<<NBLK, SCAN_BLK, 0, stream>>>(basep, bsum, cursor);
    scatter_team<<<CHUNKS * TEAMS, blk, 0, stream>>>(erow, ecol, evals,
                                                     basep, cursor, ceid, cpair);
    rowsort_pair<<<(NN + 3) / 4, blk, 0, stream>>>(basep, counts, ceid, cpair);

    float* cl = out + (size_t)NN * DD;   // out[N:2N] = cl region
    int grd = (NN + 15) / 16;            // 16 rows per 256-thread block
    const int IMAX = 0x7FFFFFFF;

    // k=0: gather from split (ue, ie); ego -> cl region only
    spmm_fused<<<grd, blk, 0, stream>>>(basep, counts, cpair,
                                        ue, ie, UCNT,
                                        noise + (size_t)0 * NN * DD,
                                        cl, nullptr, nullptr, nullptr, 0);
    // k=1: gather from cl region; ego -> x_a only
    spmm_fused<<<grd, blk, 0, stream>>>(basep, counts, cpair,
                                        cl, nullptr, IMAX,
                                        noise + (size_t)1 * NN * DD,
                                        x_a, nullptr, nullptr, nullptr, 1);
    // k=2: gather from x_a; out[0:N] = (cl + x_a + ego)/3
    spmm_fused<<<grd, blk, 0, stream>>>(basep, counts, cpair,
                                        x_a, nullptr, IMAX,
                                        noise + (size_t)2 * NN * DD,
                                        nullptr, cl, x_a, out, 2);
}

// Round 10
// 464.290 us; speedup vs baseline: 1.2878x; 1.2878x over previous
//
#include <hip/hip_runtime.h>

#define UCNT 100000
#define NN   150000
#define DD   64
#define EE   2000000
#define EPSV 0.2f

#define BROWS   64
#define NBUCK   2344                        // ceil(NN/BROWS); covers rows < 150016
#define NCHUNK  128
#define CEDGE   (EE / NCHUNK)               // 15625 (exact)
#define CAP     1536                        // bucket avg 851, sigma 29 -> +23 sigma

#define MTOT    (NBUCK * NCHUNK)            // 300032
#define SC_BLK  256
#define SC_EL   2048                        // 8 per thread
#define SC_NB   ((MTOT + SC_EL - 1) / SC_EL)  // 147

// ---- Pass A: per-(bucket,chunk) histogram --------------------------------
__global__ __launch_bounds__(512) void passA_hist(const int* __restrict__ rows,
                                                  int* __restrict__ countA) {
    __shared__ int h[NBUCK];
    for (int b = threadIdx.x; b < NBUCK; b += 512) h[b] = 0;
    __syncthreads();
    int c = blockIdx.x;
    int e0 = c * CEDGE, e1 = e0 + CEDGE;
    for (int e = e0 + threadIdx.x; e < e1; e += 512)
        atomicAdd(&h[rows[e] >> 6], 1);
    __syncthreads();
    for (int b = threadIdx.x; b < NBUCK; b += 512)
        countA[b * NCHUNK + c] = h[b];
}

// ---- exclusive scan over MTOT values (bucket-major, chunk-minor) ---------
__global__ void scanA2(const int* __restrict__ in, int* __restrict__ outx,
                       int* __restrict__ bsum) {
    int b = blockIdx.x, t = threadIdx.x;
    int i0 = b * SC_EL + t * 8;
    int v[8]; int s = 0;
    #pragma unroll
    for (int u = 0; u < 8; ++u) {
        int i = i0 + u;
        v[u] = (i < MTOT) ? in[i] : 0;
        s += v[u];
    }
    __shared__ int lds[SC_BLK];
    lds[t] = s; __syncthreads();
    for (int off = 1; off < SC_BLK; off <<= 1) {
        int add = (t >= off) ? lds[t - off] : 0;
        __syncthreads(); lds[t] += add; __syncthreads();
    }
    int excl = lds[t] - s;
    #pragma unroll
    for (int u = 0; u < 8; ++u) {
        int i = i0 + u;
        if (i < MTOT) outx[i] = excl;
        excl += v[u];
    }
    if (t == SC_BLK - 1) bsum[b] = lds[t];
}

__global__ void scanB2(int* __restrict__ bsum, int nb) {
    int t = threadIdx.x;
    int v = (t < nb) ? bsum[t] : 0;
    __shared__ int lds[SC_BLK];
    lds[t] = v; __syncthreads();
    for (int off = 1; off < SC_BLK; off <<= 1) {
        int add = (t >= off) ? lds[t - off] : 0;
        __syncthreads(); lds[t] += add; __syncthreads();
    }
    if (t < nb) bsum[t] = lds[t] - v;
}

__global__ void scanC2(int* __restrict__ outx, const int* __restrict__ bsum) {
    int b = blockIdx.x, t = threadIdx.x;
    int add = bsum[b];
    int i0 = b * SC_EL + t * 8;
    #pragma unroll
    for (int u = 0; u < 8; ++u) {
        int i = i0 + u;
        if (i < MTOT) outx[i] += add;
    }
}

// ---- Pass C: segmented scatter of (row,col,val,eid) records --------------
// Each (bucket,chunk) segment is written by exactly ONE block -> lines fill
// densely within one XCD's L2 before writeback (kills the 16x amplification).
__global__ __launch_bounds__(512) void passC_scatter(const int* __restrict__ rows,
                                                     const int* __restrict__ cols,
                                                     const float* __restrict__ vals,
                                                     const int* __restrict__ seg,
                                                     int4* __restrict__ rec) {
    __shared__ int cur[NBUCK];
    int c = blockIdx.x;
    for (int b = threadIdx.x; b < NBUCK; b += 512) cur[b] = seg[b * NCHUNK + c];
    __syncthreads();
    int e0 = c * CEDGE, e1 = e0 + CEDGE;
    for (int e = e0 + threadIdx.x; e < e1; e += 512) {
        int r = rows[e];
        int pos = atomicAdd(&cur[r >> 6], 1);
        rec[pos] = make_int4(r, cols[e], __float_as_int(vals[e]), e);
    }
}

// ---- Pass D: per-bucket finalize --------------------------------------
// Row hist + scan (produces counts[]/base[]), place into LDS row segments,
// per-row bitonic by eid (unique keys -> canonical order), coalesced emit.
__global__ __launch_bounds__(256) void passD_final(const int4* __restrict__ rec,
                                                   const int* __restrict__ seg,
                                                   int* __restrict__ counts,
                                                   int* __restrict__ basep,
                                                   int2* __restrict__ cpair) {
    int b = blockIdx.x;
    int rb = b * BROWS;
    int seg0 = seg[b * NCHUNK];
    int seg1 = (b + 1 < NBUCK) ? seg[(b + 1) * NCHUNK] : EE;
    int tot = seg1 - seg0;
    __shared__ int hist[BROWS], baseL[BROWS], cur[BROWS];
    __shared__ unsigned eidL[CAP];
    __shared__ int2 pairL[CAP];
    int t = threadIdx.x;
    if (t < BROWS) hist[t] = 0;
    __syncthreads();
    if (tot <= CAP) {
        for (int i = t; i < tot; i += 256)
            atomicAdd(&hist[rec[seg0 + i].x & (BROWS - 1)], 1);
        __syncthreads();
        if (t < BROWS) {                      // wave 0, all 64 lanes active
            int v = hist[t];
            int inc = v;
            for (int off = 1; off < BROWS; off <<= 1) {
                int o = __shfl_up(inc, off, 64);
                if (t >= off) inc += o;
            }
            baseL[t] = inc - v;
            cur[t]   = inc - v;
            int r = rb + t;
            if (r < NN) { counts[r] = v; basep[r] = seg0 + inc - v; }
        }
        __syncthreads();
        for (int i = t; i < tot; i += 256) {
            int4 q = rec[seg0 + i];
            int rl = q.x & (BROWS - 1);
            int d = atomicAdd(&cur[rl], 1);
            eidL[d]  = (unsigned)q.w;
            pairL[d] = make_int2(q.y, q.z);
        }
        __syncthreads();
        int w = t >> 6, lane = t & 63;
        for (int rl = w; rl < BROWS; rl += 4) {
            int n = hist[rl];
            if (n == 0) continue;
            int sl = baseL[rl];
            if (n <= 64) {
                unsigned key = 0xFFFFFFFFu; int pc = 0, pv = 0;
                if (lane < n) {
                    key = eidL[sl + lane];
                    int2 p = pairL[sl + lane];
                    pc = p.x; pv = p.y;
                }
                #pragma unroll
                for (int k = 2; k <= 64; k <<= 1) {
                    #pragma unroll
                    for (int j = k >> 1; j > 0; j >>= 1) {
                        unsigned ok = __shfl_xor(key, j, 64);
                        int oc = __shfl_xor(pc, j, 64), ov = __shfl_xor(pv, j, 64);
                        bool up = ((lane & k) == 0), lower = ((lane & j) == 0);
                        bool take = (lower == up) ? (ok < key) : (ok > key);
                        if (take) { key = ok; pc = oc; pv = ov; }
                    }
                }
                if (lane < n) cpair[seg0 + sl + lane] = make_int2(pc, pv);
            } else if (lane == 0) {           // ~never (needs a row with >64 edges)
                for (int i = 1; i < n; ++i) {
                    unsigned kk = eidL[sl + i]; int2 pp = pairL[sl + i];
                    int j = i - 1;
                    while (j >= 0 && eidL[sl + j] > kk) {
                        eidL[sl + j + 1]  = eidL[sl + j];
                        pairL[sl + j + 1] = pairL[sl + j];
                        --j;
                    }
                    eidL[sl + j + 1] = kk; pairL[sl + j + 1] = pp;
                }
                for (int i = 0; i < n; ++i)
                    cpair[seg0 + sl + i] = pairL[sl + i];
            }
        }
    } else if (t == 0) {
        // giant-bucket fallback (correctness only; needs bucket >CAP edges)
        int off = seg0;
        for (int r = rb; r < rb + BROWS && r < NN; ++r) {
            int cnt = 0;
            for (int i = seg0; i < seg1; ++i) if (rec[i].x == r) cnt++;
            counts[r] = cnt; basep[r] = off;
            unsigned last = 0;
            for (int m = 0; m < cnt; ++m) {
                unsigned best = 0xFFFFFFFFu; int bc = 0, bv = 0;
                for (int i = seg0; i < seg1; ++i) {
                    int4 q = rec[i];
                    if (q.x == r) {
                        unsigned ee = (unsigned)q.w;
                        if (ee >= last && ee < best) { best = ee; bc = q.y; bv = q.z; }
                    }
                }
                cpair[off + m] = make_int2(bc, bv);
                last = best + 1;
            }
            off += cnt;
        }
    }
}

// ---- fused gather-SPMM + noise perturbation (round-8-proven, unchanged) --
__device__ __forceinline__ float sgnf(float v) {
    return (v > 0.0f) ? 1.0f : ((v < 0.0f) ? -1.0f : 0.0f);
}

__global__ __launch_bounds__(256) void
spmm_fused(const int* __restrict__ base, const int* __restrict__ counts,
           const int2* __restrict__ cpair,
           const float* __restrict__ xu, const float* __restrict__ xi,
           int usplit,
           const float* __restrict__ noise_k,
           float* __restrict__ xout,
           const float* __restrict__ cl_in,
           const float* __restrict__ xa_in,
           float* __restrict__ outp,
           int k) {
    int tid = blockIdx.x * 256 + threadIdx.x;
    int row = tid >> 4;                   // 16 lanes per row
    if (row >= NN) return;
    int lane = threadIdx.x & 63;
    int q  = lane & 15;                   // dim quad within row
    int gb = lane & 48;                   // group base lane within wave

    int s = base[row];
    int n = counts[row];

    size_t ro = (size_t)row * DD + q * 4;
    float4 nv = *(const float4*)(noise_k + ro);
    float4 clv = make_float4(0.f, 0.f, 0.f, 0.f);
    float4 xav = make_float4(0.f, 0.f, 0.f, 0.f);
    if (k == 2) {
        clv = *(const float4*)(cl_in + ro);
        xav = *(const float4*)(xa_in + ro);
    }

    float4 acc = make_float4(0.f, 0.f, 0.f, 0.f);
    for (int chunk = 0; chunk < n; chunk += 16) {      // group-uniform bound
        int rem = n - chunk;
        int2 p = make_int2(0, 0);
        if (q < rem) p = cpair[s + chunk + q];         // coalesced 128B/row
        int m = (rem < 16) ? rem : 16;
        for (int i = 0; i < m; ++i) {                  // group-uniform bound
            int   c = __shfl(p.x, gb + i, 64);
            float v = __int_as_float(__shfl(p.y, gb + i, 64));
            const float* xr = (c < usplit) ? (xu + (size_t)c * DD)
                                           : (xi + (size_t)(c - usplit) * DD);
            float4 xv = ((const float4*)xr)[q];
            acc.x += v * xv.x;
            acc.y += v * xv.y;
            acc.z += v * xv.z;
            acc.w += v * xv.w;
        }
    }

    float ss = nv.x * nv.x + nv.y * nv.y + nv.z * nv.z + nv.w * nv.w;
    ss += __shfl_xor(ss, 1, 64);
    ss += __shfl_xor(ss, 2, 64);
    ss += __shfl_xor(ss, 4, 64);
    ss += __shfl_xor(ss, 8, 64);
    float scale = EPSV / fmaxf(sqrtf(ss), 1e-12f);

    float4 ego;
    ego.x = acc.x + sgnf(acc.x) * nv.x * scale;
    ego.y = acc.y + sgnf(acc.y) * nv.y * scale;
    ego.z = acc.z + sgnf(acc.z) * nv.z * scale;
    ego.w = acc.w + sgnf(acc.w) * nv.w * scale;

    if (k == 2) {
        const float inv3 = 1.0f / 3.0f;
        float4 o;
        o.x = (clv.x + xav.x + ego.x) * inv3;
        o.y = (clv.y + xav.y + ego.y) * inv3;
        o.z = (clv.z + xav.z + ego.z) * inv3;
        o.w = (clv.w + xav.w + ego.w) * inv3;
        *(float4*)(outp + ro) = o;
    } else {
        *(float4*)(xout + ro) = ego;
    }
}

extern "C" void kernel_launch(void* const* d_in, const int* in_sizes, int n_in,
                              void* d_out, int out_size, void* d_ws, size_t ws_size,
                              hipStream_t stream) {
    const float* ue    = (const float*)d_in[0];
    const float* ie    = (const float*)d_in[1];
    const int*   erow  = (const int*)  d_in[2];
    const int*   ecol  = (const int*)  d_in[3];
    const float* evals = (const float*)d_in[4];
    const float* noise = (const float*)d_in[5];
    float* out = (float*)d_out;

    // workspace layout; rec (32 MB, dead after passD) aliases x_a (38.4 MB,
    // first written in spmm k=1) — lifetimes are disjoint, stream-ordered.
    char* w = (char*)d_ws;
    float* x_a    = (float*)w;
    int4*  rec    = (int4*)w;                     w += (size_t)NN * DD * sizeof(float);
    int2*  cpair  = (int2*)w;                     w += (size_t)EE * sizeof(int2);
    int*   countA = (int*)w;                      w += (size_t)MTOT * sizeof(int);
    int*   segp   = (int*)w;                      w += (size_t)MTOT * sizeof(int);
    int*   bsum   = (int*)w;                      w += 256 * sizeof(int);
    int*   counts = (int*)w;                      w += (size_t)NN * sizeof(int);
    int*   basep  = (int*)w;                      w += (size_t)NN * sizeof(int);

    passA_hist<<<NCHUNK, 512, 0, stream>>>(erow, countA);
    scanA2<<<SC_NB, SC_BLK, 0, stream>>>(countA, segp, bsum);
    scanB2<<<1, SC_BLK, 0, stream>>>(bsum, SC_NB);
    scanC2<<<SC_NB, SC_BLK, 0, stream>>>(segp, bsum);
    passC_scatter<<<NCHUNK, 512, 0, stream>>>(erow, ecol, evals, segp, rec);
    passD_final<<<NBUCK, 256, 0, stream>>>(rec, segp, counts, basep, cpair);

    float* cl = out + (size_t)NN * DD;   // out[N:2N] = cl region
    int grd = (NN + 15) / 16;            // 16 rows per 256-thread block
    const int IMAX = 0x7FFFFFFF;

    // k=0: gather from split (ue, ie); ego -> cl region only
    spmm_fused<<<grd, 256, 0, stream>>>(basep, counts, cpair,
                                        ue, ie, UCNT,
                                        noise + (size_t)0 * NN * DD,
                                        cl, nullptr, nullptr, nullptr, 0);
    // k=1: gather from cl region; ego -> x_a only
    spmm_fused<<<grd, 256, 0, stream>>>(basep, counts, cpair,
                                        cl, nullptr, IMAX,
                                        noise + (size_t)1 * NN * DD,
                                        x_a, nullptr, nullptr, nullptr, 1);
    // k=2: gather from x_a; out[0:N] = (cl + x_a + ego)/3
    spmm_fused<<<grd, 256, 0, stream>>>(basep, counts, cpair,
                                        x_a, nullptr, IMAX,
                                        noise + (size_t)2 * NN * DD,
                                        nullptr, cl, x_a, out, 2);
}

// Round 11
// 377.156 us; speedup vs baseline: 1.5853x; 1.2310x over previous
//
#include <hip/hip_runtime.h>

#define UCNT 100000
#define NN   150000
#define DD   64
#define EE   2000000
#define EPSV 0.2f

#define BROWS   64
#define NBUCK   2344                        // ceil(NN/BROWS); covers rows < 150016
#define NCHUNK  128
#define CEDGE   (EE / NCHUNK)               // 15625 (exact)
#define CAP     1536                        // bucket avg 851, sigma 29 -> +23 sigma

#define MTOT    (NBUCK * NCHUNK)            // 300032
#define SC_BLK  256
#define SC_EL   2048                        // 8 per thread
#define SC_NB   ((MTOT + SC_EL - 1) / SC_EL)  // 147

// ---- Pass A: per-(bucket,chunk) histogram --------------------------------
__global__ __launch_bounds__(512) void passA_hist(const int* __restrict__ rows,
                                                  int* __restrict__ countA) {
    __shared__ int h[NBUCK];
    for (int b = threadIdx.x; b < NBUCK; b += 512) h[b] = 0;
    __syncthreads();
    int c = blockIdx.x;
    int e0 = c * CEDGE, e1 = e0 + CEDGE;
    for (int e = e0 + threadIdx.x; e < e1; e += 512)
        atomicAdd(&h[rows[e] >> 6], 1);
    __syncthreads();
    for (int b = threadIdx.x; b < NBUCK; b += 512)
        countA[b * NCHUNK + c] = h[b];
}

// ---- exclusive scan over MTOT values (bucket-major, chunk-minor) ---------
__global__ void scanA2(const int* __restrict__ in, int* __restrict__ outx,
                       int* __restrict__ bsum) {
    int b = blockIdx.x, t = threadIdx.x;
    int i0 = b * SC_EL + t * 8;
    int v[8]; int s = 0;
    #pragma unroll
    for (int u = 0; u < 8; ++u) {
        int i = i0 + u;
        v[u] = (i < MTOT) ? in[i] : 0;
        s += v[u];
    }
    __shared__ int lds[SC_BLK];
    lds[t] = s; __syncthreads();
    for (int off = 1; off < SC_BLK; off <<= 1) {
        int add = (t >= off) ? lds[t - off] : 0;
        __syncthreads(); lds[t] += add; __syncthreads();
    }
    int excl = lds[t] - s;
    #pragma unroll
    for (int u = 0; u < 8; ++u) {
        int i = i0 + u;
        if (i < MTOT) outx[i] = excl;
        excl += v[u];
    }
    if (t == SC_BLK - 1) bsum[b] = lds[t];
}

__global__ void scanB2(int* __restrict__ bsum, int nb) {
    int t = threadIdx.x;
    int v = (t < nb) ? bsum[t] : 0;
    __shared__ int lds[SC_BLK];
    lds[t] = v; __syncthreads();
    for (int off = 1; off < SC_BLK; off <<= 1) {
        int add = (t >= off) ? lds[t - off] : 0;
        __syncthreads(); lds[t] += add; __syncthreads();
    }
    if (t < nb) bsum[t] = lds[t] - v;
}

__global__ void scanC2(int* __restrict__ outx, const int* __restrict__ bsum) {
    int b = blockIdx.x, t = threadIdx.x;
    int add = bsum[b];
    int i0 = b * SC_EL + t * 8;
    #pragma unroll
    for (int u = 0; u < 8; ++u) {
        int i = i0 + u;
        if (i < MTOT) outx[i] += add;
    }
}

// ---- Pass C: segmented scatter of (row,col,val,eid) records --------------
__global__ __launch_bounds__(512) void passC_scatter(const int* __restrict__ rows,
                                                     const int* __restrict__ cols,
                                                     const float* __restrict__ vals,
                                                     const int* __restrict__ seg,
                                                     int4* __restrict__ rec) {
    __shared__ int cur[NBUCK];
    int c = blockIdx.x;
    for (int b = threadIdx.x; b < NBUCK; b += 512) cur[b] = seg[b * NCHUNK + c];
    __syncthreads();
    int e0 = c * CEDGE, e1 = e0 + CEDGE;
    for (int e = e0 + threadIdx.x; e < e1; e += 512) {
        int r = rows[e];
        int pos = atomicAdd(&cur[r >> 6], 1);
        rec[pos] = make_int4(r, cols[e], __float_as_int(vals[e]), e);
    }
}

// ---- Pass D: per-bucket finalize -----------------------------------------
// Row hist + scan, LDS placement, then size-adaptive bitonic by eid:
// pass 1 sorts 4 rows at once (16-wide nets, commits n<=16, ~82% of rows);
// pass 2 sorts big rows 2 at once (32-wide nets), 64-wide for n<=64,
// serial fallback beyond. Distinct eid keys -> canonical result regardless
// of the non-deterministic LDS placement order.
__global__ __launch_bounds__(256) void passD_final(const int4* __restrict__ rec,
                                                   const int* __restrict__ seg,
                                                   int* __restrict__ counts,
                                                   int* __restrict__ basep,
                                                   int2* __restrict__ cpair) {
    int b = blockIdx.x;
    int rb = b * BROWS;
    int seg0 = seg[b * NCHUNK];
    int seg1 = (b + 1 < NBUCK) ? seg[(b + 1) * NCHUNK] : EE;
    int tot = seg1 - seg0;
    __shared__ int hist[BROWS], baseL[BROWS], cur[BROWS];
    __shared__ unsigned eidL[CAP];
    __shared__ int2 pairL[CAP];
    int t = threadIdx.x;
    if (t < BROWS) hist[t] = 0;
    __syncthreads();
    if (tot <= CAP) {
        for (int i = t; i < tot; i += 256)
            atomicAdd(&hist[rec[seg0 + i].x & (BROWS - 1)], 1);
        __syncthreads();
        if (t < BROWS) {                      // wave 0, all 64 lanes active
            int v = hist[t];
            int inc = v;
            for (int off = 1; off < BROWS; off <<= 1) {
                int o = __shfl_up(inc, off, 64);
                if (t >= off) inc += o;
            }
            baseL[t] = inc - v;
            cur[t]   = inc - v;
            int r = rb + t;
            if (r < NN) { counts[r] = v; basep[r] = seg0 + inc - v; }
        }
        __syncthreads();
        for (int i = t; i < tot; i += 256) {
            int4 q = rec[seg0 + i];
            int rl = q.x & (BROWS - 1);
            int d = atomicAdd(&cur[rl], 1);
            eidL[d]  = (unsigned)q.w;
            pairL[d] = make_int2(q.y, q.z);
        }
        __syncthreads();
        int w = t >> 6, lane = t & 63;
        int r0w = w * 16;                     // this wave's 16 rows
        // ---- pass 1: 4 rows per iteration, independent 16-wide networks
        for (int g = 0; g < 16; g += 4) {
            int rl = r0w + g + (lane >> 4);
            int n  = hist[rl];
            int l16 = lane & 15;
            int sl = baseL[rl];
            bool use = (n <= 16) && (l16 < n);
            unsigned key = 0xFFFFFFFFu; int pc = 0, pv = 0;
            if (use) {
                key = eidL[sl + l16];
                int2 p = pairL[sl + l16];
                pc = p.x; pv = p.y;
            }
            #pragma unroll
            for (int k = 2; k <= 16; k <<= 1) {
                #pragma unroll
                for (int j = k >> 1; j > 0; j >>= 1) {
                    unsigned ok = __shfl_xor(key, j, 64);
                    int oc = __shfl_xor(pc, j, 64), ov = __shfl_xor(pv, j, 64);
                    bool up = ((l16 & k) == 0), lower = ((l16 & j) == 0);
                    bool take = (lower == up) ? (ok < key) : (ok > key);
                    if (take) { key = ok; pc = oc; pv = ov; }
                }
            }
            if (use) cpair[seg0 + sl + l16] = make_int2(pc, pv);
        }
        // ---- pass 2: big rows (n>16), two at a time, 32-wide networks
        {
            int myn = (lane < 16) ? hist[r0w + lane] : 0;
            unsigned long long big = __ballot(lane < 16 && myn > 16);
            while (big) {
                int ia = __ffsll((long long)big) - 1; big &= big - 1;
                int ib = -1;
                if (big) { ib = __ffsll((long long)big) - 1; big &= big - 1; }
                int na = hist[r0w + ia];
                int nb2 = (ib >= 0) ? hist[r0w + ib] : 0;
                if (na <= 32 && nb2 <= 32) {
                    int rid = (lane < 32) ? ia : ((ib >= 0) ? ib : ia);
                    int rl  = r0w + rid;
                    int n   = (lane < 32) ? na : nb2;
                    int l32 = lane & 31;
                    int sl  = baseL[rl];
                    bool act = (lane < 32) || (ib >= 0);
                    bool use = act && (l32 < n);
                    unsigned key = 0xFFFFFFFFu; int pc = 0, pv = 0;
                    if (use) {
                        key = eidL[sl + l32];
                        int2 p = pairL[sl + l32];
                        pc = p.x; pv = p.y;
                    }
                    #pragma unroll
                    for (int k = 2; k <= 32; k <<= 1) {
                        #pragma unroll
                        for (int j = k >> 1; j > 0; j >>= 1) {
                            unsigned ok = __shfl_xor(key, j, 64);
                            int oc = __shfl_xor(pc, j, 64), ov = __shfl_xor(pv, j, 64);
                            bool up = ((l32 & k) == 0), lower = ((l32 & j) == 0);
                            bool take = (lower == up) ? (ok < key) : (ok > key);
                            if (take) { key = ok; pc = oc; pv = ov; }
                        }
                    }
                    if (use) cpair[seg0 + sl + l32] = make_int2(pc, pv);
                } else {
                    for (int ps = 0; ps < 2; ++ps) {
                        int rid = (ps == 0) ? ia : ib;
                        if (rid < 0) continue;
                        int rl = r0w + rid;
                        int n = hist[rl];
                        int sl = baseL[rl];
                        if (n <= 16) continue;            // already done in pass 1
                        if (n <= 64) {
                            unsigned key = 0xFFFFFFFFu; int pc = 0, pv = 0;
                            if (lane < n) {
                                key = eidL[sl + lane];
                                int2 p = pairL[sl + lane];
                                pc = p.x; pv = p.y;
                            }
                            #pragma unroll
                            for (int k = 2; k <= 64; k <<= 1) {
                                #pragma unroll
                                for (int j = k >> 1; j > 0; j >>= 1) {
                                    unsigned ok = __shfl_xor(key, j, 64);
                                    int oc = __shfl_xor(pc, j, 64), ov = __shfl_xor(pv, j, 64);
                                    bool up = ((lane & k) == 0), lower = ((lane & j) == 0);
                                    bool take = (lower == up) ? (ok < key) : (ok > key);
                                    if (take) { key = ok; pc = oc; pv = ov; }
                                }
                            }
                            if (lane < n) cpair[seg0 + sl + lane] = make_int2(pc, pv);
                        } else if (lane == 0) {           // n>64: ~impossible, serial
                            for (int i = 1; i < n; ++i) {
                                unsigned kk = eidL[sl + i]; int2 pp = pairL[sl + i];
                                int j = i - 1;
                                while (j >= 0 && eidL[sl + j] > kk) {
                                    eidL[sl + j + 1]  = eidL[sl + j];
                                    pairL[sl + j + 1] = pairL[sl + j];
                                    --j;
                                }
                                eidL[sl + j + 1] = kk; pairL[sl + j + 1] = pp;
                            }
                            for (int i = 0; i < n; ++i)
                                cpair[seg0 + sl + i] = pairL[sl + i];
                        }
                    }
                }
            }
        }
    } else if (t == 0) {
        // giant-bucket fallback (correctness only; needs bucket >CAP edges)
        int off = seg0;
        for (int r = rb; r < rb + BROWS && r < NN; ++r) {
            int cnt = 0;
            for (int i = seg0; i < seg1; ++i) if (rec[i].x == r) cnt++;
            counts[r] = cnt; basep[r] = off;
            unsigned last = 0;
            for (int m = 0; m < cnt; ++m) {
                unsigned best = 0xFFFFFFFFu; int bc = 0, bv = 0;
                for (int i = seg0; i < seg1; ++i) {
                    int4 q = rec[i];
                    if (q.x == r) {
                        unsigned ee = (unsigned)q.w;
                        if (ee >= last && ee < best) { best = ee; bc = q.y; bv = q.z; }
                    }
                }
                cpair[off + m] = make_int2(bc, bv);
                last = best + 1;
            }
            off += cnt;
        }
    }
}

// ---- fused gather-SPMM + noise perturbation (round-8-proven, unchanged) --
__device__ __forceinline__ float sgnf(float v) {
    return (v > 0.0f) ? 1.0f : ((v < 0.0f) ? -1.0f : 0.0f);
}

__global__ __launch_bounds__(256) void
spmm_fused(const int* __restrict__ base, const int* __restrict__ counts,
           const int2* __restrict__ cpair,
           const float* __restrict__ xu, const float* __restrict__ xi,
           int usplit,
           const float* __restrict__ noise_k,
           float* __restrict__ xout,
           const float* __restrict__ cl_in,
           const float* __restrict__ xa_in,
           float* __restrict__ outp,
           int k) {
    int tid = blockIdx.x * 256 + threadIdx.x;
    int row = tid >> 4;                   // 16 lanes per row
    if (row >= NN) return;
    int lane = threadIdx.x & 63;
    int q  = lane & 15;                   // dim quad within row
    int gb = lane & 48;                   // group base lane within wave

    int s = base[row];
    int n = counts[row];

    size_t ro = (size_t)row * DD + q * 4;
    float4 nv = *(const float4*)(noise_k + ro);
    float4 clv = make_float4(0.f, 0.f, 0.f, 0.f);
    float4 xav = make_float4(0.f, 0.f, 0.f, 0.f);
    if (k == 2) {
        clv = *(const float4*)(cl_in + ro);
        xav = *(const float4*)(xa_in + ro);
    }

    float4 acc = make_float4(0.f, 0.f, 0.f, 0.f);
    for (int chunk = 0; chunk < n; chunk += 16) {      // group-uniform bound
        int rem = n - chunk;
        int2 p = make_int2(0, 0);
        if (q < rem) p = cpair[s + chunk + q];         // coalesced 128B/row
        int m = (rem < 16) ? rem : 16;
        for (int i = 0; i < m; ++i) {                  // group-uniform bound
            int   c = __shfl(p.x, gb + i, 64);
            float v = __int_as_float(__shfl(p.y, gb + i, 64));
            const float* xr = (c < usplit) ? (xu + (size_t)c * DD)
                                           : (xi + (size_t)(c - usplit) * DD);
            float4 xv = ((const float4*)xr)[q];
            acc.x += v * xv.x;
            acc.y += v * xv.y;
            acc.z += v * xv.z;
            acc.w += v * xv.w;
        }
    }

    float ss = nv.x * nv.x + nv.y * nv.y + nv.z * nv.z + nv.w * nv.w;
    ss += __shfl_xor(ss, 1, 64);
    ss += __shfl_xor(ss, 2, 64);
    ss += __shfl_xor(ss, 4, 64);
    ss += __shfl_xor(ss, 8, 64);
    float scale = EPSV / fmaxf(sqrtf(ss), 1e-12f);

    float4 ego;
    ego.x = acc.x + sgnf(acc.x) * nv.x * scale;
    ego.y = acc.y + sgnf(acc.y) * nv.y * scale;
    ego.z = acc.z + sgnf(acc.z) * nv.z * scale;
    ego.w = acc.w + sgnf(acc.w) * nv.w * scale;

    if (k == 2) {
        const float inv3 = 1.0f / 3.0f;
        float4 o;
        o.x = (clv.x + xav.x + ego.x) * inv3;
        o.y = (clv.y + xav.y + ego.y) * inv3;
        o.z = (clv.z + xav.z + ego.z) * inv3;
        o.w = (clv.w + xav.w + ego.w) * inv3;
        *(float4*)(outp + ro) = o;
    } else {
        *(float4*)(xout + ro) = ego;
    }
}

extern "C" void kernel_launch(void* const* d_in, const int* in_sizes, int n_in,
                              void* d_out, int out_size, void* d_ws, size_t ws_size,
                              hipStream_t stream) {
    const float* ue    = (const float*)d_in[0];
    const float* ie    = (const float*)d_in[1];
    const int*   erow  = (const int*)  d_in[2];
    const int*   ecol  = (const int*)  d_in[3];
    const float* evals = (const float*)d_in[4];
    const float* noise = (const float*)d_in[5];
    float* out = (float*)d_out;

    // workspace layout; rec (32 MB, dead after passD) aliases x_a (38.4 MB,
    // first written in spmm k=1) — lifetimes are disjoint, stream-ordered.
    char* w = (char*)d_ws;
    float* x_a    = (float*)w;
    int4*  rec    = (int4*)w;                     w += (size_t)NN * DD * sizeof(float);
    int2*  cpair  = (int2*)w;                     w += (size_t)EE * sizeof(int2);
    int*   countA = (int*)w;                      w += (size_t)MTOT * sizeof(int);
    int*   segp   = (int*)w;                      w += (size_t)MTOT * sizeof(int);
    int*   bsum   = (int*)w;                      w += 256 * sizeof(int);
    int*   counts = (int*)w;                      w += (size_t)NN * sizeof(int);
    int*   basep  = (int*)w;                      w += (size_t)NN * sizeof(int);

    passA_hist<<<NCHUNK, 512, 0, stream>>>(erow, countA);
    scanA2<<<SC_NB, SC_BLK, 0, stream>>>(countA, segp, bsum);
    scanB2<<<1, SC_BLK, 0, stream>>>(bsum, SC_NB);
    scanC2<<<SC_NB, SC_BLK, 0, stream>>>(segp, bsum);
    passC_scatter<<<NCHUNK, 512, 0, stream>>>(erow, ecol, evals, segp, rec);
    passD_final<<<NBUCK, 256, 0, stream>>>(rec, segp, counts, basep, cpair);

    float* cl = out + (size_t)NN * DD;   // out[N:2N] = cl region
    int grd = (NN + 15) / 16;            // 16 rows per 256-thread block
    const int IMAX = 0x7FFFFFFF;

    // k=0: gather from split (ue, ie); ego -> cl region only
    spmm_fused<<<grd, 256, 0, stream>>>(basep, counts, cpair,
                                        ue, ie, UCNT,
                                        noise + (size_t)0 * NN * DD,
                                        cl, nullptr, nullptr, nullptr, 0);
    // k=1: gather from cl region; ego -> x_a only
    spmm_fused<<<grd, 256, 0, stream>>>(basep, counts, cpair,
                                        cl, nullptr, IMAX,
                                        noise + (size_t)1 * NN * DD,
                                        x_a, nullptr, nullptr, nullptr, 1);
    // k=2: gather from x_a; out[0:N] = (cl + x_a + ego)/3
    spmm_fused<<<grd, 256, 0, stream>>>(basep, counts, cpair,
                                        x_a, nullptr, IMAX,
                                        noise + (size_t)2 * NN * DD,
                                        nullptr, cl, x_a, out, 2);
}

// Round 12
// 372.908 us; speedup vs baseline: 1.6034x; 1.0114x over previous
//
#include <hip/hip_runtime.h>

#define UCNT 100000
#define NN   150000
#define DD   64
#define EE   2000000
#define EPSV 0.2f

#define BROWS   64
#define NBUCK   2344                        // ceil(NN/BROWS); covers rows < 150016
#define NCHUNK  128
#define CEDGE   (EE / NCHUNK)               // 15625 (exact)
#define CAP     1536                        // bucket avg 851, sigma 29 -> +23 sigma

#define MTOT    (NBUCK * NCHUNK)            // 300032
#define SC_BLK  256
#define SC_EL   2048                        // 8 per thread
#define SC_NB   ((MTOT + SC_EL - 1) / SC_EL)  // 147

// ---- Pass A: per-(bucket,chunk) histogram --------------------------------
__global__ __launch_bounds__(512) void passA_hist(const int* __restrict__ rows,
                                                  int* __restrict__ countA) {
    __shared__ int h[NBUCK];
    for (int b = threadIdx.x; b < NBUCK; b += 512) h[b] = 0;
    __syncthreads();
    int c = blockIdx.x;
    int e0 = c * CEDGE, e1 = e0 + CEDGE;
    for (int e = e0 + threadIdx.x; e < e1; e += 512)
        atomicAdd(&h[rows[e] >> 6], 1);
    __syncthreads();
    for (int b = threadIdx.x; b < NBUCK; b += 512)
        countA[b * NCHUNK + c] = h[b];
}

// ---- exclusive scan over MTOT values (bucket-major, chunk-minor) ---------
__global__ void scanA2(const int* __restrict__ in, int* __restrict__ outx,
                       int* __restrict__ bsum) {
    int b = blockIdx.x, t = threadIdx.x;
    int i0 = b * SC_EL + t * 8;
    int v[8]; int s = 0;
    #pragma unroll
    for (int u = 0; u < 8; ++u) {
        int i = i0 + u;
        v[u] = (i < MTOT) ? in[i] : 0;
        s += v[u];
    }
    __shared__ int lds[SC_BLK];
    lds[t] = s; __syncthreads();
    for (int off = 1; off < SC_BLK; off <<= 1) {
        int add = (t >= off) ? lds[t - off] : 0;
        __syncthreads(); lds[t] += add; __syncthreads();
    }
    int excl = lds[t] - s;
    #pragma unroll
    for (int u = 0; u < 8; ++u) {
        int i = i0 + u;
        if (i < MTOT) outx[i] = excl;
        excl += v[u];
    }
    if (t == SC_BLK - 1) bsum[b] = lds[t];
}

__global__ void scanB2(int* __restrict__ bsum, int nb) {
    int t = threadIdx.x;
    int v = (t < nb) ? bsum[t] : 0;
    __shared__ int lds[SC_BLK];
    lds[t] = v; __syncthreads();
    for (int off = 1; off < SC_BLK; off <<= 1) {
        int add = (t >= off) ? lds[t - off] : 0;
        __syncthreads(); lds[t] += add; __syncthreads();
    }
    if (t < nb) bsum[t] = lds[t] - v;
}

__global__ void scanC2(int* __restrict__ outx, const int* __restrict__ bsum) {
    int b = blockIdx.x, t = threadIdx.x;
    int add = bsum[b];
    int i0 = b * SC_EL + t * 8;
    #pragma unroll
    for (int u = 0; u < 8; ++u) {
        int i = i0 + u;
        if (i < MTOT) outx[i] += add;
    }
}

// ---- Pass C: segmented scatter of (row,col,val,eid) records --------------
__global__ __launch_bounds__(512) void passC_scatter(const int* __restrict__ rows,
                                                     const int* __restrict__ cols,
                                                     const float* __restrict__ vals,
                                                     const int* __restrict__ seg,
                                                     int4* __restrict__ rec) {
    __shared__ int cur[NBUCK];
    int c = blockIdx.x;
    for (int b = threadIdx.x; b < NBUCK; b += 512) cur[b] = seg[b * NCHUNK + c];
    __syncthreads();
    int e0 = c * CEDGE, e1 = e0 + CEDGE;
    for (int e = e0 + threadIdx.x; e < e1; e += 512) {
        int r = rows[e];
        int pos = atomicAdd(&cur[r >> 6], 1);
        rec[pos] = make_int4(r, cols[e], __float_as_int(vals[e]), e);
    }
}

// ---- Pass D: per-bucket finalize (round-11-proven, unchanged) ------------
__global__ __launch_bounds__(256) void passD_final(const int4* __restrict__ rec,
                                                   const int* __restrict__ seg,
                                                   int* __restrict__ counts,
                                                   int* __restrict__ basep,
                                                   int2* __restrict__ cpair) {
    int b = blockIdx.x;
    int rb = b * BROWS;
    int seg0 = seg[b * NCHUNK];
    int seg1 = (b + 1 < NBUCK) ? seg[(b + 1) * NCHUNK] : EE;
    int tot = seg1 - seg0;
    __shared__ int hist[BROWS], baseL[BROWS], cur[BROWS];
    __shared__ unsigned eidL[CAP];
    __shared__ int2 pairL[CAP];
    int t = threadIdx.x;
    if (t < BROWS) hist[t] = 0;
    __syncthreads();
    if (tot <= CAP) {
        for (int i = t; i < tot; i += 256)
            atomicAdd(&hist[rec[seg0 + i].x & (BROWS - 1)], 1);
        __syncthreads();
        if (t < BROWS) {                      // wave 0, all 64 lanes active
            int v = hist[t];
            int inc = v;
            for (int off = 1; off < BROWS; off <<= 1) {
                int o = __shfl_up(inc, off, 64);
                if (t >= off) inc += o;
            }
            baseL[t] = inc - v;
            cur[t]   = inc - v;
            int r = rb + t;
            if (r < NN) { counts[r] = v; basep[r] = seg0 + inc - v; }
        }
        __syncthreads();
        for (int i = t; i < tot; i += 256) {
            int4 q = rec[seg0 + i];
            int rl = q.x & (BROWS - 1);
            int d = atomicAdd(&cur[rl], 1);
            eidL[d]  = (unsigned)q.w;
            pairL[d] = make_int2(q.y, q.z);
        }
        __syncthreads();
        int w = t >> 6, lane = t & 63;
        int r0w = w * 16;                     // this wave's 16 rows
        // ---- pass 1: 4 rows per iteration, independent 16-wide networks
        for (int g = 0; g < 16; g += 4) {
            int rl = r0w + g + (lane >> 4);
            int n  = hist[rl];
            int l16 = lane & 15;
            int sl = baseL[rl];
            bool use = (n <= 16) && (l16 < n);
            unsigned key = 0xFFFFFFFFu; int pc = 0, pv = 0;
            if (use) {
                key = eidL[sl + l16];
                int2 p = pairL[sl + l16];
                pc = p.x; pv = p.y;
            }
            #pragma unroll
            for (int k = 2; k <= 16; k <<= 1) {
                #pragma unroll
                for (int j = k >> 1; j > 0; j >>= 1) {
                    unsigned ok = __shfl_xor(key, j, 64);
                    int oc = __shfl_xor(pc, j, 64), ov = __shfl_xor(pv, j, 64);
                    bool up = ((l16 & k) == 0), lower = ((l16 & j) == 0);
                    bool take = (lower == up) ? (ok < key) : (ok > key);
                    if (take) { key = ok; pc = oc; pv = ov; }
                }
            }
            if (use) cpair[seg0 + sl + l16] = make_int2(pc, pv);
        }
        // ---- pass 2: big rows (n>16), two at a time, 32-wide networks
        {
            int myn = (lane < 16) ? hist[r0w + lane] : 0;
            unsigned long long big = __ballot(lane < 16 && myn > 16);
            while (big) {
                int ia = __ffsll((long long)big) - 1; big &= big - 1;
                int ib = -1;
                if (big) { ib = __ffsll((long long)big) - 1; big &= big - 1; }
                int na = hist[r0w + ia];
                int nb2 = (ib >= 0) ? hist[r0w + ib] : 0;
                if (na <= 32 && nb2 <= 32) {
                    int rid = (lane < 32) ? ia : ((ib >= 0) ? ib : ia);
                    int rl  = r0w + rid;
                    int n   = (lane < 32) ? na : nb2;
                    int l32 = lane & 31;
                    int sl  = baseL[rl];
                    bool act = (lane < 32) || (ib >= 0);
                    bool use = act && (l32 < n);
                    unsigned key = 0xFFFFFFFFu; int pc = 0, pv = 0;
                    if (use) {
                        key = eidL[sl + l32];
                        int2 p = pairL[sl + l32];
                        pc = p.x; pv = p.y;
                    }
                    #pragma unroll
                    for (int k = 2; k <= 32; k <<= 1) {
                        #pragma unroll
                        for (int j = k >> 1; j > 0; j >>= 1) {
                            unsigned ok = __shfl_xor(key, j, 64);
                            int oc = __shfl_xor(pc, j, 64), ov = __shfl_xor(pv, j, 64);
                            bool up = ((l32 & k) == 0), lower = ((l32 & j) == 0);
                            bool take = (lower == up) ? (ok < key) : (ok > key);
                            if (take) { key = ok; pc = oc; pv = ov; }
                        }
                    }
                    if (use) cpair[seg0 + sl + l32] = make_int2(pc, pv);
                } else {
                    for (int ps = 0; ps < 2; ++ps) {
                        int rid = (ps == 0) ? ia : ib;
                        if (rid < 0) continue;
                        int rl = r0w + rid;
                        int n = hist[rl];
                        int sl = baseL[rl];
                        if (n <= 16) continue;            // already done in pass 1
                        if (n <= 64) {
                            unsigned key = 0xFFFFFFFFu; int pc = 0, pv = 0;
                            if (lane < n) {
                                key = eidL[sl + lane];
                                int2 p = pairL[sl + lane];
                                pc = p.x; pv = p.y;
                            }
                            #pragma unroll
                            for (int k = 2; k <= 64; k <<= 1) {
                                #pragma unroll
                                for (int j = k >> 1; j > 0; j >>= 1) {
                                    unsigned ok = __shfl_xor(key, j, 64);
                                    int oc = __shfl_xor(pc, j, 64), ov = __shfl_xor(pv, j, 64);
                                    bool up = ((lane & k) == 0), lower = ((lane & j) == 0);
                                    bool take = (lower == up) ? (ok < key) : (ok > key);
                                    if (take) { key = ok; pc = oc; pv = ov; }
                                }
                            }
                            if (lane < n) cpair[seg0 + sl + lane] = make_int2(pc, pv);
                        } else if (lane == 0) {           // n>64: ~impossible, serial
                            for (int i = 1; i < n; ++i) {
                                unsigned kk = eidL[sl + i]; int2 pp = pairL[sl + i];
                                int j = i - 1;
                                while (j >= 0 && eidL[sl + j] > kk) {
                                    eidL[sl + j + 1]  = eidL[sl + j];
                                    pairL[sl + j + 1] = pairL[sl + j];
                                    --j;
                                }
                                eidL[sl + j + 1] = kk; pairL[sl + j + 1] = pp;
                            }
                            for (int i = 0; i < n; ++i)
                                cpair[seg0 + sl + i] = pairL[sl + i];
                        }
                    }
                }
            }
        }
    } else if (t == 0) {
        // giant-bucket fallback (correctness only; needs bucket >CAP edges)
        int off = seg0;
        for (int r = rb; r < rb + BROWS && r < NN; ++r) {
            int cnt = 0;
            for (int i = seg0; i < seg1; ++i) if (rec[i].x == r) cnt++;
            counts[r] = cnt; basep[r] = off;
            unsigned last = 0;
            for (int m = 0; m < cnt; ++m) {
                unsigned best = 0xFFFFFFFFu; int bc = 0, bv = 0;
                for (int i = seg0; i < seg1; ++i) {
                    int4 q = rec[i];
                    if (q.x == r) {
                        unsigned ee = (unsigned)q.w;
                        if (ee >= last && ee < best) { best = ee; bc = q.y; bv = q.z; }
                    }
                }
                cpair[off + m] = make_int2(bc, bv);
                last = best + 1;
            }
            off += cnt;
        }
    }
}

// ---- fused gather-SPMM + noise perturbation ------------------------------
// 16 lanes per row, 4 rows per wave. Per 16-edge chunk: ALL gathers are
// issued back-to-back into statically-indexed registers (full unroll ->
// stays in VGPRs, 16 loads in flight per wave), then FMA'd in strict
// e0<e1<... order (identical summation order to rounds 8-11).
__device__ __forceinline__ float sgnf(float v) {
    return (v > 0.0f) ? 1.0f : ((v < 0.0f) ? -1.0f : 0.0f);
}

__global__ __launch_bounds__(256) void
spmm_fused(const int* __restrict__ base, const int* __restrict__ counts,
           const int2* __restrict__ cpair,
           const float* __restrict__ xu, const float* __restrict__ xi,
           int usplit,
           const float* __restrict__ noise_k,
           float* __restrict__ xout,
           const float* __restrict__ cl_in,
           const float* __restrict__ xa_in,
           float* __restrict__ outp,
           int k) {
    int tid = blockIdx.x * 256 + threadIdx.x;
    int row = tid >> 4;                   // 16 lanes per row
    if (row >= NN) return;
    int lane = threadIdx.x & 63;
    int q  = lane & 15;                   // dim quad within row
    int gb = lane & 48;                   // group base lane within wave

    int s = base[row];
    int n = counts[row];

    size_t ro = (size_t)row * DD + q * 4;
    float4 nv = *(const float4*)(noise_k + ro);
    float4 clv = make_float4(0.f, 0.f, 0.f, 0.f);
    float4 xav = make_float4(0.f, 0.f, 0.f, 0.f);
    if (k == 2) {
        clv = *(const float4*)(cl_in + ro);
        xav = *(const float4*)(xa_in + ro);
    }

    float4 acc = make_float4(0.f, 0.f, 0.f, 0.f);
    for (int chunk = 0; chunk < n; chunk += 16) {      // group-uniform bound
        int rem = n - chunk;
        int m = (rem < 16) ? rem : 16;                 // group-uniform
        int2 p = make_int2(0, 0);
        if (q < rem) p = cpair[s + chunk + q];         // coalesced 128B/row

        float  vv[16];
        float4 xv[16];
        #pragma unroll
        for (int i = 0; i < 16; ++i) {                 // issue all gathers
            int   c = __shfl(p.x, gb + i, 64);
            vv[i]   = __int_as_float(__shfl(p.y, gb + i, 64));
            if (i < m) {
                const float* xr = (c < usplit) ? (xu + (size_t)c * DD)
                                               : (xi + (size_t)(c - usplit) * DD);
                xv[i] = ((const float4*)xr)[q];
            }
        }
        #pragma unroll
        for (int i = 0; i < 16; ++i) {                 // strict eid order
            if (i < m) {
                acc.x += vv[i] * xv[i].x;
                acc.y += vv[i] * xv[i].y;
                acc.z += vv[i] * xv[i].z;
                acc.w += vv[i] * xv[i].w;
            }
        }
    }

    float ss = nv.x * nv.x + nv.y * nv.y + nv.z * nv.z + nv.w * nv.w;
    ss += __shfl_xor(ss, 1, 64);
    ss += __shfl_xor(ss, 2, 64);
    ss += __shfl_xor(ss, 4, 64);
    ss += __shfl_xor(ss, 8, 64);
    float scale = EPSV / fmaxf(sqrtf(ss), 1e-12f);

    float4 ego;
    ego.x = acc.x + sgnf(acc.x) * nv.x * scale;
    ego.y = acc.y + sgnf(acc.y) * nv.y * scale;
    ego.z = acc.z + sgnf(acc.z) * nv.z * scale;
    ego.w = acc.w + sgnf(acc.w) * nv.w * scale;

    if (k == 2) {
        const float inv3 = 1.0f / 3.0f;
        float4 o;
        o.x = (clv.x + xav.x + ego.x) * inv3;
        o.y = (clv.y + xav.y + ego.y) * inv3;
        o.z = (clv.z + xav.z + ego.z) * inv3;
        o.w = (clv.w + xav.w + ego.w) * inv3;
        *(float4*)(outp + ro) = o;
    } else {
        *(float4*)(xout + ro) = ego;
    }
}

extern "C" void kernel_launch(void* const* d_in, const int* in_sizes, int n_in,
                              void* d_out, int out_size, void* d_ws, size_t ws_size,
                              hipStream_t stream) {
    const float* ue    = (const float*)d_in[0];
    const float* ie    = (const float*)d_in[1];
    const int*   erow  = (const int*)  d_in[2];
    const int*   ecol  = (const int*)  d_in[3];
    const float* evals = (const float*)d_in[4];
    const float* noise = (const float*)d_in[5];
    float* out = (float*)d_out;

    // workspace layout; rec (32 MB, dead after passD) aliases x_a (38.4 MB,
    // first written in spmm k=1) — lifetimes are disjoint, stream-ordered.
    char* w = (char*)d_ws;
    float* x_a    = (float*)w;
    int4*  rec    = (int4*)w;                     w += (size_t)NN * DD * sizeof(float);
    int2*  cpair  = (int2*)w;                     w += (size_t)EE * sizeof(int2);
    int*   countA = (int*)w;                      w += (size_t)MTOT * sizeof(int);
    int*   segp   = (int*)w;                      w += (size_t)MTOT * sizeof(int);
    int*   bsum   = (int*)w;                      w += 256 * sizeof(int);
    int*   counts = (int*)w;                      w += (size_t)NN * sizeof(int);
    int*   basep  = (int*)w;                      w += (size_t)NN * sizeof(int);

    passA_hist<<<NCHUNK, 512, 0, stream>>>(erow, countA);
    scanA2<<<SC_NB, SC_BLK, 0, stream>>>(countA, segp, bsum);
    scanB2<<<1, SC_BLK, 0, stream>>>(bsum, SC_NB);
    scanC2<<<SC_NB, SC_BLK, 0, stream>>>(segp, bsum);
    passC_scatter<<<NCHUNK, 512, 0, stream>>>(erow, ecol, evals, segp, rec);
    passD_final<<<NBUCK, 256, 0, stream>>>(rec, segp, counts, basep, cpair);

    float* cl = out + (size_t)NN * DD;   // out[N:2N] = cl region
    int grd = (NN + 15) / 16;            // 16 rows per 256-thread block
    const int IMAX = 0x7FFFFFFF;

    // k=0: gather from split (ue, ie); ego -> cl region only
    spmm_fused<<<grd, 256, 0, stream>>>(basep, counts, cpair,
                                        ue, ie, UCNT,
                                        noise + (size_t)0 * NN * DD,
                                        cl, nullptr, nullptr, nullptr, 0);
    // k=1: gather from cl region; ego -> x_a only
    spmm_fused<<<grd, 256, 0, stream>>>(basep, counts, cpair,
                                        cl, nullptr, IMAX,
                                        noise + (size_t)1 * NN * DD,
                                        x_a, nullptr, nullptr, nullptr, 1);
    // k=2: gather from x_a; out[0:N] = (cl + x_a + ego)/3
    spmm_fused<<<grd, 256, 0, stream>>>(basep, counts, cpair,
                                        x_a, nullptr, IMAX,
                                        noise + (size_t)2 * NN * DD,
                                        nullptr, cl, x_a, out, 2);
}

// Round 13
// 359.448 us; speedup vs baseline: 1.6634x; 1.0374x over previous
//
#include <hip/hip_runtime.h>

#define UCNT 100000
#define NN   150000
#define DD   64
#define EE   2000000
#define EPSV 0.2f

#define BROWS   64
#define NBUCK   2344                        // ceil(NN/BROWS); covers rows < 150016
#define NCHUNK  128
#define CEDGE   15628                       // multiple of 4 (int4-aligned chunks)
#define CAP     1536                        // bucket avg 851, sigma 29 -> +23 sigma

#define MTOT    (NBUCK * NCHUNK)            // 300032
#define SC_BLK  256
#define SC_EL   2048                        // 8 per thread
#define SC_NB   ((MTOT + SC_EL - 1) / SC_EL)  // 147

// ---- Pass A: per-(bucket,chunk) histogram (int4-vectorized) --------------
__global__ __launch_bounds__(512) void passA_hist(const int* __restrict__ rows,
                                                  int* __restrict__ countA) {
    __shared__ int h[NBUCK];
    for (int b = threadIdx.x; b < NBUCK; b += 512) h[b] = 0;
    __syncthreads();
    int c = blockIdx.x;
    int e0 = c * CEDGE;
    int e1 = e0 + CEDGE; if (e1 > EE) e1 = EE;
    const int4* rows4 = (const int4*)rows;
    for (int i4 = (e0 >> 2) + threadIdx.x; i4 < (e1 >> 2); i4 += 512) {
        int4 r4 = rows4[i4];
        atomicAdd(&h[r4.x >> 6], 1);
        atomicAdd(&h[r4.y >> 6], 1);
        atomicAdd(&h[r4.z >> 6], 1);
        atomicAdd(&h[r4.w >> 6], 1);
    }
    __syncthreads();
    for (int b = threadIdx.x; b < NBUCK; b += 512)
        countA[b * NCHUNK + c] = h[b];
}

// ---- exclusive scan over MTOT values (bucket-major, chunk-minor) ---------
__global__ void scanA2(const int* __restrict__ in, int* __restrict__ outx,
                       int* __restrict__ bsum) {
    int b = blockIdx.x, t = threadIdx.x;
    int i0 = b * SC_EL + t * 8;
    int v[8]; int s = 0;
    #pragma unroll
    for (int u = 0; u < 8; ++u) {
        int i = i0 + u;
        v[u] = (i < MTOT) ? in[i] : 0;
        s += v[u];
    }
    __shared__ int lds[SC_BLK];
    lds[t] = s; __syncthreads();
    for (int off = 1; off < SC_BLK; off <<= 1) {
        int add = (t >= off) ? lds[t - off] : 0;
        __syncthreads(); lds[t] += add; __syncthreads();
    }
    int excl = lds[t] - s;
    #pragma unroll
    for (int u = 0; u < 8; ++u) {
        int i = i0 + u;
        if (i < MTOT) outx[i] = excl;
        excl += v[u];
    }
    if (t == SC_BLK - 1) bsum[b] = lds[t];
}

__global__ void scanB2(int* __restrict__ bsum, int nb) {
    int t = threadIdx.x;
    int v = (t < nb) ? bsum[t] : 0;
    __shared__ int lds[SC_BLK];
    lds[t] = v; __syncthreads();
    for (int off = 1; off < SC_BLK; off <<= 1) {
        int add = (t >= off) ? lds[t - off] : 0;
        __syncthreads(); lds[t] += add; __syncthreads();
    }
    if (t < nb) bsum[t] = lds[t] - v;
}

__global__ void scanC2(int* __restrict__ outx, const int* __restrict__ bsum) {
    int b = blockIdx.x, t = threadIdx.x;
    int add = bsum[b];
    int i0 = b * SC_EL + t * 8;
    #pragma unroll
    for (int u = 0; u < 8; ++u) {
        int i = i0 + u;
        if (i < MTOT) outx[i] += add;
    }
}

// ---- Pass C: segmented scatter of (row,col,val,eid) records (int4 reads) -
__global__ __launch_bounds__(512) void passC_scatter(const int* __restrict__ rows,
                                                     const int* __restrict__ cols,
                                                     const float* __restrict__ vals,
                                                     const int* __restrict__ seg,
                                                     int4* __restrict__ rec) {
    __shared__ int cur[NBUCK];
    int c = blockIdx.x;
    for (int b = threadIdx.x; b < NBUCK; b += 512) cur[b] = seg[b * NCHUNK + c];
    __syncthreads();
    int e0 = c * CEDGE;
    int e1 = e0 + CEDGE; if (e1 > EE) e1 = EE;
    const int4*   rows4 = (const int4*)rows;
    const int4*   cols4 = (const int4*)cols;
    const float4* vals4 = (const float4*)vals;
    for (int i4 = (e0 >> 2) + threadIdx.x; i4 < (e1 >> 2); i4 += 512) {
        int4   r4 = rows4[i4];
        int4   c4 = cols4[i4];
        float4 v4 = vals4[i4];
        int e = i4 << 2;
        int pos;
        pos = atomicAdd(&cur[r4.x >> 6], 1);
        rec[pos] = make_int4(r4.x, c4.x, __float_as_int(v4.x), e + 0);
        pos = atomicAdd(&cur[r4.y >> 6], 1);
        rec[pos] = make_int4(r4.y, c4.y, __float_as_int(v4.y), e + 1);
        pos = atomicAdd(&cur[r4.z >> 6], 1);
        rec[pos] = make_int4(r4.z, c4.z, __float_as_int(v4.z), e + 2);
        pos = atomicAdd(&cur[r4.w >> 6], 1);
        rec[pos] = make_int4(r4.w, c4.w, __float_as_int(v4.w), e + 3);
    }
}

// ---- Pass D: per-bucket finalize (round-11-proven, unchanged) ------------
__global__ __launch_bounds__(256) void passD_final(const int4* __restrict__ rec,
                                                   const int* __restrict__ seg,
                                                   int* __restrict__ counts,
                                                   int* __restrict__ basep,
                                                   int2* __restrict__ cpair) {
    int b = blockIdx.x;
    int rb = b * BROWS;
    int seg0 = seg[b * NCHUNK];
    int seg1 = (b + 1 < NBUCK) ? seg[(b + 1) * NCHUNK] : EE;
    int tot = seg1 - seg0;
    __shared__ int hist[BROWS], baseL[BROWS], cur[BROWS];
    __shared__ unsigned eidL[CAP];
    __shared__ int2 pairL[CAP];
    int t = threadIdx.x;
    if (t < BROWS) hist[t] = 0;
    __syncthreads();
    if (tot <= CAP) {
        for (int i = t; i < tot; i += 256)
            atomicAdd(&hist[rec[seg0 + i].x & (BROWS - 1)], 1);
        __syncthreads();
        if (t < BROWS) {                      // wave 0, all 64 lanes active
            int v = hist[t];
            int inc = v;
            for (int off = 1; off < BROWS; off <<= 1) {
                int o = __shfl_up(inc, off, 64);
                if (t >= off) inc += o;
            }
            baseL[t] = inc - v;
            cur[t]   = inc - v;
            int r = rb + t;
            if (r < NN) { counts[r] = v; basep[r] = seg0 + inc - v; }
        }
        __syncthreads();
        for (int i = t; i < tot; i += 256) {
            int4 q = rec[seg0 + i];
            int rl = q.x & (BROWS - 1);
            int d = atomicAdd(&cur[rl], 1);
            eidL[d]  = (unsigned)q.w;
            pairL[d] = make_int2(q.y, q.z);
        }
        __syncthreads();
        int w = t >> 6, lane = t & 63;
        int r0w = w * 16;                     // this wave's 16 rows
        // ---- pass 1: 4 rows per iteration, independent 16-wide networks
        for (int g = 0; g < 16; g += 4) {
            int rl = r0w + g + (lane >> 4);
            int n  = hist[rl];
            int l16 = lane & 15;
            int sl = baseL[rl];
            bool use = (n <= 16) && (l16 < n);
            unsigned key = 0xFFFFFFFFu; int pc = 0, pv = 0;
            if (use) {
                key = eidL[sl + l16];
                int2 p = pairL[sl + l16];
                pc = p.x; pv = p.y;
            }
            #pragma unroll
            for (int k = 2; k <= 16; k <<= 1) {
                #pragma unroll
                for (int j = k >> 1; j > 0; j >>= 1) {
                    unsigned ok = __shfl_xor(key, j, 64);
                    int oc = __shfl_xor(pc, j, 64), ov = __shfl_xor(pv, j, 64);
                    bool up = ((l16 & k) == 0), lower = ((l16 & j) == 0);
                    bool take = (lower == up) ? (ok < key) : (ok > key);
                    if (take) { key = ok; pc = oc; pv = ov; }
                }
            }
            if (use) cpair[seg0 + sl + l16] = make_int2(pc, pv);
        }
        // ---- pass 2: big rows (n>16), two at a time, 32-wide networks
        {
            int myn = (lane < 16) ? hist[r0w + lane] : 0;
            unsigned long long big = __ballot(lane < 16 && myn > 16);
            while (big) {
                int ia = __ffsll((long long)big) - 1; big &= big - 1;
                int ib = -1;
                if (big) { ib = __ffsll((long long)big) - 1; big &= big - 1; }
                int na = hist[r0w + ia];
                int nb2 = (ib >= 0) ? hist[r0w + ib] : 0;
                if (na <= 32 && nb2 <= 32) {
                    int rid = (lane < 32) ? ia : ((ib >= 0) ? ib : ia);
                    int rl  = r0w + rid;
                    int n   = (lane < 32) ? na : nb2;
                    int l32 = lane & 31;
                    int sl  = baseL[rl];
                    bool act = (lane < 32) || (ib >= 0);
                    bool use = act && (l32 < n);
                    unsigned key = 0xFFFFFFFFu; int pc = 0, pv = 0;
                    if (use) {
                        key = eidL[sl + l32];
                        int2 p = pairL[sl + l32];
                        pc = p.x; pv = p.y;
                    }
                    #pragma unroll
                    for (int k = 2; k <= 32; k <<= 1) {
                        #pragma unroll
                        for (int j = k >> 1; j > 0; j >>= 1) {
                            unsigned ok = __shfl_xor(key, j, 64);
                            int oc = __shfl_xor(pc, j, 64), ov = __shfl_xor(pv, j, 64);
                            bool up = ((l32 & k) == 0), lower = ((l32 & j) == 0);
                            bool take = (lower == up) ? (ok < key) : (ok > key);
                            if (take) { key = ok; pc = oc; pv = ov; }
                        }
                    }
                    if (use) cpair[seg0 + sl + l32] = make_int2(pc, pv);
                } else {
                    for (int ps = 0; ps < 2; ++ps) {
                        int rid = (ps == 0) ? ia : ib;
                        if (rid < 0) continue;
                        int rl = r0w + rid;
                        int n = hist[rl];
                        int sl = baseL[rl];
                        if (n <= 16) continue;            // already done in pass 1
                        if (n <= 64) {
                            unsigned key = 0xFFFFFFFFu; int pc = 0, pv = 0;
                            if (lane < n) {
                                key = eidL[sl + lane];
                                int2 p = pairL[sl + lane];
                                pc = p.x; pv = p.y;
                            }
                            #pragma unroll
                            for (int k = 2; k <= 64; k <<= 1) {
                                #pragma unroll
                                for (int j = k >> 1; j > 0; j >>= 1) {
                                    unsigned ok = __shfl_xor(key, j, 64);
                                    int oc = __shfl_xor(pc, j, 64), ov = __shfl_xor(pv, j, 64);
                                    bool up = ((lane & k) == 0), lower = ((lane & j) == 0);
                                    bool take = (lower == up) ? (ok < key) : (ok > key);
                                    if (take) { key = ok; pc = oc; pv = ov; }
                                }
                            }
                            if (lane < n) cpair[seg0 + sl + lane] = make_int2(pc, pv);
                        } else if (lane == 0) {           // n>64: ~impossible, serial
                            for (int i = 1; i < n; ++i) {
                                unsigned kk = eidL[sl + i]; int2 pp = pairL[sl + i];
                                int j = i - 1;
                                while (j >= 0 && eidL[sl + j] > kk) {
                                    eidL[sl + j + 1]  = eidL[sl + j];
                                    pairL[sl + j + 1] = pairL[sl + j];
                                    --j;
                                }
                                eidL[sl + j + 1] = kk; pairL[sl + j + 1] = pp;
                            }
                            for (int i = 0; i < n; ++i)
                                cpair[seg0 + sl + i] = pairL[sl + i];
                        }
                    }
                }
            }
        }
    } else if (t == 0) {
        // giant-bucket fallback (correctness only; needs bucket >CAP edges)
        int off = seg0;
        for (int r = rb; r < rb + BROWS && r < NN; ++r) {
            int cnt = 0;
            for (int i = seg0; i < seg1; ++i) if (rec[i].x == r) cnt++;
            counts[r] = cnt; basep[r] = off;
            unsigned last = 0;
            for (int m = 0; m < cnt; ++m) {
                unsigned best = 0xFFFFFFFFu; int bc = 0, bv = 0;
                for (int i = seg0; i < seg1; ++i) {
                    int4 q = rec[i];
                    if (q.x == r) {
                        unsigned ee = (unsigned)q.w;
                        if (ee >= last && ee < best) { best = ee; bc = q.y; bv = q.z; }
                    }
                }
                cpair[off + m] = make_int2(bc, bv);
                last = best + 1;
            }
            off += cnt;
        }
    }
}

// ---- fused gather-SPMM + noise perturbation (round-12, unchanged) --------
__device__ __forceinline__ float sgnf(float v) {
    return (v > 0.0f) ? 1.0f : ((v < 0.0f) ? -1.0f : 0.0f);
}

__global__ __launch_bounds__(256) void
spmm_fused(const int* __restrict__ base, const int* __restrict__ counts,
           const int2* __restrict__ cpair,
           const float* __restrict__ xu, const float* __restrict__ xi,
           int usplit,
           const float* __restrict__ noise_k,
           float* __restrict__ xout,
           const float* __restrict__ cl_in,
           const float* __restrict__ xa_in,
           float* __restrict__ outp,
           int k) {
    int tid = blockIdx.x * 256 + threadIdx.x;
    int row = tid >> 4;                   // 16 lanes per row
    if (row >= NN) return;
    int lane = threadIdx.x & 63;
    int q  = lane & 15;                   // dim quad within row
    int gb = lane & 48;                   // group base lane within wave

    int s = base[row];
    int n = counts[row];

    size_t ro = (size_t)row * DD + q * 4;
    float4 nv = *(const float4*)(noise_k + ro);
    float4 clv = make_float4(0.f, 0.f, 0.f, 0.f);
    float4 xav = make_float4(0.f, 0.f, 0.f, 0.f);
    if (k == 2) {
        clv = *(const float4*)(cl_in + ro);
        xav = *(const float4*)(xa_in + ro);
    }

    float4 acc = make_float4(0.f, 0.f, 0.f, 0.f);
    for (int chunk = 0; chunk < n; chunk += 16) {      // group-uniform bound
        int rem = n - chunk;
        int m = (rem < 16) ? rem : 16;                 // group-uniform
        int2 p = make_int2(0, 0);
        if (q < rem) p = cpair[s + chunk + q];         // coalesced 128B/row

        float  vv[16];
        float4 xv[16];
        #pragma unroll
        for (int i = 0; i < 16; ++i) {                 // issue all gathers
            int   c = __shfl(p.x, gb + i, 64);
            vv[i]   = __int_as_float(__shfl(p.y, gb + i, 64));
            if (i < m) {
                const float* xr = (c < usplit) ? (xu + (size_t)c * DD)
                                               : (xi + (size_t)(c - usplit) * DD);
                xv[i] = ((const float4*)xr)[q];
            }
        }
        #pragma unroll
        for (int i = 0; i < 16; ++i) {                 // strict eid order
            if (i < m) {
                acc.x += vv[i] * xv[i].x;
                acc.y += vv[i] * xv[i].y;
                acc.z += vv[i] * xv[i].z;
                acc.w += vv[i] * xv[i].w;
            }
        }
    }

    float ss = nv.x * nv.x + nv.y * nv.y + nv.z * nv.z + nv.w * nv.w;
    ss += __shfl_xor(ss, 1, 64);
    ss += __shfl_xor(ss, 2, 64);
    ss += __shfl_xor(ss, 4, 64);
    ss += __shfl_xor(ss, 8, 64);
    float scale = EPSV / fmaxf(sqrtf(ss), 1e-12f);

    float4 ego;
    ego.x = acc.x + sgnf(acc.x) * nv.x * scale;
    ego.y = acc.y + sgnf(acc.y) * nv.y * scale;
    ego.z = acc.z + sgnf(acc.z) * nv.z * scale;
    ego.w = acc.w + sgnf(acc.w) * nv.w * scale;

    if (k == 2) {
        const float inv3 = 1.0f / 3.0f;
        float4 o;
        o.x = (clv.x + xav.x + ego.x) * inv3;
        o.y = (clv.y + xav.y + ego.y) * inv3;
        o.z = (clv.z + xav.z + ego.z) * inv3;
        o.w = (clv.w + xav.w + ego.w) * inv3;
        *(float4*)(outp + ro) = o;
    } else {
        *(float4*)(xout + ro) = ego;
    }
}

extern "C" void kernel_launch(void* const* d_in, const int* in_sizes, int n_in,
                              void* d_out, int out_size, void* d_ws, size_t ws_size,
                              hipStream_t stream) {
    const float* ue    = (const float*)d_in[0];
    const float* ie    = (const float*)d_in[1];
    const int*   erow  = (const int*)  d_in[2];
    const int*   ecol  = (const int*)  d_in[3];
    const float* evals = (const float*)d_in[4];
    const float* noise = (const float*)d_in[5];
    float* out = (float*)d_out;

    // workspace layout; rec (32 MB, dead after passD) aliases x_a (38.4 MB,
    // first written in spmm k=1) — lifetimes are disjoint, stream-ordered.
    char* w = (char*)d_ws;
    float* x_a    = (float*)w;
    int4*  rec    = (int4*)w;                     w += (size_t)NN * DD * sizeof(float);
    int2*  cpair  = (int2*)w;                     w += (size_t)EE * sizeof(int2);
    int*   countA = (int*)w;                      w += (size_t)MTOT * sizeof(int);
    int*   segp   = (int*)w;                      w += (size_t)MTOT * sizeof(int);
    int*   bsum   = (int*)w;                      w += 256 * sizeof(int);
    int*   counts = (int*)w;                      w += (size_t)NN * sizeof(int);
    int*   basep  = (int*)w;                      w += (size_t)NN * sizeof(int);

    passA_hist<<<NCHUNK, 512, 0, stream>>>(erow, countA);
    scanA2<<<SC_NB, SC_BLK, 0, stream>>>(countA, segp, bsum);
    scanB2<<<1, SC_BLK, 0, stream>>>(bsum, SC_NB);
    scanC2<<<SC_NB, SC_BLK, 0, stream>>>(segp, bsum);
    passC_scatter<<<NCHUNK, 512, 0, stream>>>(erow, ecol, evals, segp, rec);
    passD_final<<<NBUCK, 256, 0, stream>>>(rec, segp, counts, basep, cpair);

    float* cl = out + (size_t)NN * DD;   // out[N:2N] = cl region
    int grd = (NN + 15) / 16;            // 16 rows per 256-thread block
    const int IMAX = 0x7FFFFFFF;

    // k=0: gather from split (ue, ie); ego -> cl region only
    spmm_fused<<<grd, 256, 0, stream>>>(basep, counts, cpair,
                                        ue, ie, UCNT,
                                        noise + (size_t)0 * NN * DD,
                                        cl, nullptr, nullptr, nullptr, 0);
    // k=1: gather from cl region; ego -> x_a only
    spmm_fused<<<grd, 256, 0, stream>>>(basep, counts, cpair,
                                        cl, nullptr, IMAX,
                                        noise + (size_t)1 * NN * DD,
                                        x_a, nullptr, nullptr, nullptr, 1);
    // k=2: gather from x_a; out[0:N] = (cl + x_a + ego)/3
    spmm_fused<<<grd, 256, 0, stream>>>(basep, counts, cpair,
                                        x_a, nullptr, IMAX,
                                        noise + (size_t)2 * NN * DD,
                                        nullptr, cl, x_a, out, 2);
}